// Round 1
// baseline (474.039 us; speedup 1.0000x reference)
//
#include <hip/hip_runtime.h>
#include <hip/hip_bf16.h>

// RelationalNet forward, MI355X (gfx950).
// Structure:
//   conv1..4 (stride2 pad1 + relu) -> per-block BN partial stats -> BN reduce/finalize
//   (BN folded into next consumer as per-channel scale/shift)
//   build A/Bm/Qv   : factorized g layer-1 (pairs@gw1 = A[q]+Bm[p]+Qv)
//   prep_w          : gw2/3/4 f32 -> bf16 in MFMA-fragment order
//   g_fused         : per 64 pair-rows: act1 -> (MFMA 256x256) x3 -> masked row-sum partials
//   f_phi           : reduce partials, 2x dense+relu, 256->10, log_softmax
// Workspace requirement: 13,296,832 floats = 53.2 MB.

typedef __attribute__((ext_vector_type(8))) short short8;
typedef __attribute__((ext_vector_type(4))) float floatx4;

__device__ __forceinline__ unsigned short f2bf(float v){
  union { float f; unsigned int u; } c; c.f = v;
  unsigned int u = c.u;
  u += 0x7FFFu + ((u >> 16) & 1u);   // round-to-nearest-even
  return (unsigned short)(u >> 16);
}

// ---------------- conv + relu + per-block BN partial stats ----------------
template<int CI, int COG>
__global__ __launch_bounds__(256) void conv_relu_stats(
    const float* __restrict__ in, const float* __restrict__ ss,
    const float* __restrict__ cw, const float* __restrict__ cb,
    float* __restrict__ out, float* __restrict__ pstats,
    int H, int W, int OH, int OW)
{
  const int co0 = blockIdx.y * COG;
  __shared__ float wsm[COG*CI*9];
  __shared__ float ssm[2*CI];
  __shared__ float psum[4*COG], psum2[4*COG];
  const int tid = threadIdx.x;
  for (int j = tid; j < COG*CI*9; j += 256) wsm[j] = cw[co0*CI*9 + j];
  if (ss) { for (int j = tid; j < 2*CI; j += 256) ssm[j] = ss[j]; }
  else    { for (int j = tid; j < 2*CI; j += 256) ssm[j] = (j < CI) ? 1.f : 0.f; }
  __syncthreads();
  const int idx = blockIdx.x*256 + tid;          // grids are exact multiples of 256
  const int ow = idx % OW; const int t2 = idx / OW;
  const int oh = t2 % OH;  const int b  = t2 / OH;
  float accv[COG];
  #pragma unroll
  for (int g = 0; g < COG; g++) accv[g] = cb[co0+g];
  for (int ci = 0; ci < CI; ci++){
    const float* ip = in + ((long)(b*CI+ci))*H*W;
    const float sc = ssm[ci], sh = ssm[CI+ci];
    #pragma unroll
    for (int kh = 0; kh < 3; kh++){
      const int ih = oh*2 - 1 + kh;
      if ((unsigned)ih >= (unsigned)H) continue;      // zero-padding: contributes 0
      #pragma unroll
      for (int kw = 0; kw < 3; kw++){
        const int iw = ow*2 - 1 + kw;
        if ((unsigned)iw >= (unsigned)W) continue;
        const float v = ip[ih*W + iw] * sc + sh;       // folded BN of previous layer
        #pragma unroll
        for (int g = 0; g < COG; g++)
          accv[g] += v * wsm[(g*CI+ci)*9 + kh*3 + kw];
      }
    }
  }
  const int wave = tid >> 6, lane = tid & 63;
  #pragma unroll
  for (int g = 0; g < COG; g++){
    const float v = fmaxf(accv[g], 0.f);
    out[(((long)b*24 + co0+g)*OH + oh)*OW + ow] = v;
    float s = v, s2 = v*v;
    for (int off = 32; off; off >>= 1){ s += __shfl_down(s, off); s2 += __shfl_down(s2, off); }
    if (lane == 0){ psum[wave*COG+g] = s; psum2[wave*COG+g] = s2; }
  }
  __syncthreads();
  if (tid < COG){
    float S = 0.f, S2 = 0.f;
    #pragma unroll
    for (int w = 0; w < 4; w++){ S += psum[w*COG+tid]; S2 += psum2[w*COG+tid]; }
    pstats[blockIdx.x*48 + co0 + tid]      = S;
    pstats[blockIdx.x*48 + 24 + co0 + tid] = S2;
  }
}

// ------------- reduce per-block stats -> scale/shift (gamma*(x-m)*rs+beta) -------------
__global__ __launch_bounds__(256) void bn_reduce_finalize(
    const float* __restrict__ pstats, int nblk,
    const float* __restrict__ gamma, const float* __restrict__ beta,
    float* __restrict__ ss, float invN)
{
  const int c = blockIdx.x;           // 0..23
  const int tid = threadIdx.x;
  float s = 0.f, s2 = 0.f;
  for (int j = tid; j < nblk; j += 256){ s += pstats[j*48 + c]; s2 += pstats[j*48 + 24 + c]; }
  for (int off = 32; off; off >>= 1){ s += __shfl_down(s, off); s2 += __shfl_down(s2, off); }
  __shared__ float ps[4], ps2[4];
  const int wave = tid >> 6, lane = tid & 63;
  if (lane == 0){ ps[wave] = s; ps2[wave] = s2; }
  __syncthreads();
  if (tid == 0){
    const float S  = ps[0]+ps[1]+ps[2]+ps[3];
    const float S2 = ps2[0]+ps2[1]+ps2[2]+ps2[3];
    const float mean = S * invN;
    const float var  = S2 * invN - mean*mean;      // biased var (ddof=0), matches jnp.var
    const float rs   = rsqrtf(var + 1e-5f);
    const float sc   = gamma[c] * rs;
    ss[c]      = sc;
    ss[24 + c] = beta[c] - mean * sc;
  }
}

// ------------- gw2/3/4 f32 -> bf16 in MFMA B-fragment order -------------
// layout: wf[((kk*16 + t)*64 + lane)*8 + i] = W[kk*32 + (lane>>4)*8 + i][t*16 + (lane&15)]
__global__ __launch_bounds__(256) void prep_w(
    const float* __restrict__ gw, unsigned short* __restrict__ wf)
{
  const int idx = blockIdx.x*256 + threadIdx.x;   // 65536 total
  const int i = idx & 7, lane = (idx >> 3) & 63, t = (idx >> 9) & 15, kk = idx >> 13;
  const int k = kk*32 + (lane >> 4)*8 + i;
  const int c = t*16 + (lane & 15);
  wf[idx] = f2bf(gw[k*256 + c]);
}

// ------------- Qv[b][n] = gb1[n] + qst[b] @ gw1[52:63] -------------
__global__ __launch_bounds__(256) void build_Qv(
    const float* __restrict__ qst, const float* __restrict__ gw1,
    const float* __restrict__ gb1, float* __restrict__ Qv)
{
  const int b = blockIdx.x, n = threadIdx.x;
  float acc = gb1[n];
  #pragma unroll
  for (int j = 0; j < 11; j++) acc += qst[b*11 + j] * gw1[(52 + j)*256 + n];
  Qv[b*256 + n] = acc;
}

// ------------- A[bq] = obj[b,q] @ gw1[0:26] ; Bm[bq] = obj[b,q] @ gw1[26:52] -------------
__global__ __launch_bounds__(256) void build_AB(
    const float* __restrict__ y4, const float* __restrict__ ss4,
    const float* __restrict__ gw1, float* __restrict__ A, float* __restrict__ Bm)
{
  const int bq = blockIdx.x;            // 0..6399
  const int b = bq / 25, q = bq % 25;
  __shared__ float orow[26];
  const int tid = threadIdx.x;
  if (tid < 24)        orow[tid] = ss4[tid] * y4[((long)(b*24 + tid))*25 + q] + ss4[24 + tid];
  else if (tid == 24)  orow[24] = (float)(q/5 - 2) * 0.5f;
  else if (tid == 25)  orow[25] = (float)(q%5 - 2) * 0.5f;
  __syncthreads();
  float a = 0.f, bb = 0.f;
  #pragma unroll
  for (int c = 0; c < 26; c++){
    const float o = orow[c];
    a  += o * gw1[c*256 + tid];
    bb += o * gw1[(26 + c)*256 + tid];
  }
  A [(long)bq*256 + tid] = a;
  Bm[(long)bq*256 + tid] = bb;
}

// ------------- fused g_theta layers 2..4 + masked row-sum -------------
// block: 64 pair-rows of one batch, 4 waves; wave w owns cols [64w, 64w+64).
// act: bf16 row-major [64][256] in LDS, XOR-swizzled (byte ^= (row&7)<<4) for
// conflict-free ds_read_b128 A-fragments (G4). Weights staged 32-K-rows at a
// time from fragment-ordered global (linear copy, lane-consecutive B reads).
__global__ __launch_bounds__(256) void g_fused(
    const float* __restrict__ A, const float* __restrict__ Bm, const float* __restrict__ Qv,
    const unsigned short* __restrict__ Wf,
    const float* __restrict__ gb2, const float* __restrict__ gb3, const float* __restrict__ gb4,
    float* __restrict__ gpart)
{
  __shared__ __align__(16) short act[64*256];   // 32 KB
  __shared__ __align__(16) short wt[32*256];    // 16 KB (also final f32 scratch)
  const int tid = threadIdx.x;
  const int bidx = blockIdx.x;
  const int b = bidx / 10, blk = bidx % 10;
  const int rowbase = blk * 64;
  const int nrows = min(64, 625 - rowbase);     // last block: 49
  char* actB = (char*)act;

  // ---- layer-1 activations: act = relu(A[q] + Bm[p] + Qv), bf16, swizzled ----
  {
    const int r  = tid >> 2;                    // local row; same wave that later reads it
    const int c0 = (tid & 3) * 64;
    if (r < nrows){
      const int row = rowbase + r;              // pair index p*25+q
      const float* ap = A  + ((long)(b*25 + row % 25))*256 + c0;
      const float* bp = Bm + ((long)(b*25 + row / 25))*256 + c0;
      const float* qp = Qv + b*256 + c0;
      #pragma unroll
      for (int j = 0; j < 64; j += 4){
        floatx4 av = *(const floatx4*)(ap + j);
        floatx4 bv = *(const floatx4*)(bp + j);
        floatx4 qv = *(const floatx4*)(qp + j);
        unsigned int p0 = (unsigned int)f2bf(fmaxf(av.x+bv.x+qv.x, 0.f))
                        | ((unsigned int)f2bf(fmaxf(av.y+bv.y+qv.y, 0.f)) << 16);
        unsigned int p1 = (unsigned int)f2bf(fmaxf(av.z+bv.z+qv.z, 0.f))
                        | ((unsigned int)f2bf(fmaxf(av.w+bv.w+qv.w, 0.f)) << 16);
        const int byte = (r*512 + (c0+j)*2) ^ ((r & 7) << 4);
        *(uint2*)(actB + byte) = make_uint2(p0, p1);
      }
    } else {
      #pragma unroll
      for (int j = 0; j < 64; j += 4){
        const int byte = (r*512 + (c0+j)*2) ^ ((r & 7) << 4);
        *(uint2*)(actB + byte) = make_uint2(0u, 0u);   // padded rows: zero (masked at sum)
      }
    }
  }

  const int wave = tid >> 6, lane = tid & 63;
  const int lmod = lane & 15, ldiv = lane >> 4;

  floatx4 acc[4][4];
  for (int L = 0; L < 3; L++){
    #pragma unroll
    for (int m = 0; m < 4; m++)
      #pragma unroll
      for (int n = 0; n < 4; n++)
        acc[m][n] = (floatx4){0.f,0.f,0.f,0.f};
    const uint4* wsrc = (const uint4*)(Wf + L*65536);
    const short8* wfr = (const short8*)wt;
    for (int kk = 0; kk < 8; kk++){
      __syncthreads();                                  // prior wt reads done
      {
        const uint4* s = wsrc + kk*1024;
        uint4* d = (uint4*)wt;
        #pragma unroll
        for (int j = 0; j < 4; j++) d[tid + j*256] = s[tid + j*256];
      }
      __syncthreads();                                  // wt (and, at kk==0, act) ready
      short8 af[4];
      #pragma unroll
      for (int m = 0; m < 4; m++){
        const int arow  = m*16 + lmod;
        const int abyte = (arow*512 + kk*64 + ldiv*16) ^ ((arow & 7) << 4);
        af[m] = *(const short8*)(actB + abyte);
      }
      #pragma unroll
      for (int n = 0; n < 4; n++){
        const short8 bfv = wfr[(4*wave + n)*64 + lane];
        #pragma unroll
        for (int m = 0; m < 4; m++)
          acc[m][n] = __builtin_amdgcn_mfma_f32_16x16x32_bf16(af[m], bfv, acc[m][n], 0, 0, 0);
      }
    }
    const float* bias = (L == 0) ? gb2 : (L == 1) ? gb3 : gb4;
    __syncthreads();   // WAR: all waves' A-reads done before act overwrite / wt reuse
    if (L < 2){
      // D layout: row = m*16 + (lane>>4)*4 + i, col = (4w+n)*16 + (lane&15)   [m89]
      #pragma unroll
      for (int n = 0; n < 4; n++){
        const int c = (4*wave + n)*16 + lmod;
        const float bv = bias[c];
        #pragma unroll
        for (int m = 0; m < 4; m++){
          #pragma unroll
          for (int i = 0; i < 4; i++){
            const int row = m*16 + ldiv*4 + i;
            const float v = fmaxf(acc[m][n][i] + bv, 0.f);
            const int byte = (row*512 + c*2) ^ ((row & 7) << 4);
            *(short*)(actB + byte) = (short)f2bf(v);
          }
        }
      }
    } else {
      float* scratch = (float*)wt;
      #pragma unroll
      for (int n = 0; n < 4; n++){
        const int c = (4*wave + n)*16 + lmod;
        const float bv = bias[c];
        float s = 0.f;
        #pragma unroll
        for (int m = 0; m < 4; m++){
          #pragma unroll
          for (int i = 0; i < 4; i++){
            const int row = m*16 + ldiv*4 + i;
            const float v = fmaxf(acc[m][n][i] + bv, 0.f);
            if (row < nrows) s += v;                    // mask padded rows
          }
        }
        s += __shfl_xor(s, 16);
        s += __shfl_xor(s, 32);
        if (ldiv == 0) scratch[c] = s;                  // each wave owns distinct cols
      }
      __syncthreads();
      gpart[(long)bidx*256 + tid] = scratch[tid];
    }
  }
}

// ------------- reduce partials + f_phi + log_softmax -------------
__global__ __launch_bounds__(256) void f_phi(
    const float* __restrict__ gpart,
    const float* __restrict__ fw1, const float* __restrict__ fb1,
    const float* __restrict__ fw2, const float* __restrict__ fb2,
    const float* __restrict__ fw3, const float* __restrict__ fb3,
    float* __restrict__ out)
{
  const int b = blockIdx.x, n = threadIdx.x;
  __shared__ float bufA[256], bufB[256], lg[10];
  float g = 0.f;
  #pragma unroll
  for (int j = 0; j < 10; j++) g += gpart[((long)(b*10 + j))*256 + n];
  bufA[n] = g;
  __syncthreads();
  float acc = fb1[n];
  for (int k = 0; k < 256; k++) acc += bufA[k] * fw1[k*256 + n];
  bufB[n] = fmaxf(acc, 0.f);
  __syncthreads();
  acc = fb2[n];
  for (int k = 0; k < 256; k++) acc += bufB[k] * fw2[k*256 + n];
  __syncthreads();
  bufA[n] = fmaxf(acc, 0.f);
  __syncthreads();
  if (n < 10){
    float a3 = fb3[n];
    for (int k = 0; k < 256; k++) a3 += bufA[k] * fw3[k*10 + n];
    lg[n] = a3;
  }
  __syncthreads();
  if (n < 10){
    float m = lg[0];
    #pragma unroll
    for (int j = 1; j < 10; j++) m = fmaxf(m, lg[j]);
    float s = 0.f;
    #pragma unroll
    for (int j = 0; j < 10; j++) s += expf(lg[j] - m);
    out[b*10 + n] = lg[n] - m - logf(s);
  }
}

extern "C" void kernel_launch(void* const* d_in, const int* in_sizes, int n_in,
                              void* d_out, int out_size, void* d_ws, size_t ws_size,
                              hipStream_t stream)
{
  const float* x   = (const float*)d_in[0];
  const float* qst = (const float*)d_in[1];
  const float* cw1 = (const float*)d_in[2];
  const float* cb1 = (const float*)d_in[3];
  const float* bg1 = (const float*)d_in[4];
  const float* bb1 = (const float*)d_in[5];
  const float* cw2 = (const float*)d_in[6];
  const float* cb2 = (const float*)d_in[7];
  const float* bg2 = (const float*)d_in[8];
  const float* bb2 = (const float*)d_in[9];
  const float* cw3 = (const float*)d_in[10];
  const float* cb3 = (const float*)d_in[11];
  const float* bg3 = (const float*)d_in[12];
  const float* bb3 = (const float*)d_in[13];
  const float* cw4 = (const float*)d_in[14];
  const float* cb4 = (const float*)d_in[15];
  const float* bg4 = (const float*)d_in[16];
  const float* bb4 = (const float*)d_in[17];
  const float* gw1 = (const float*)d_in[18];
  const float* gb1 = (const float*)d_in[19];
  const float* gw2 = (const float*)d_in[20];
  const float* gb2 = (const float*)d_in[21];
  const float* gw3 = (const float*)d_in[22];
  const float* gb3 = (const float*)d_in[23];
  const float* gw4 = (const float*)d_in[24];
  const float* gb4 = (const float*)d_in[25];
  const float* fw1 = (const float*)d_in[26];
  const float* fb1 = (const float*)d_in[27];
  const float* fw2 = (const float*)d_in[28];
  const float* fb2 = (const float*)d_in[29];
  const float* fw3 = (const float*)d_in[30];
  const float* fb3 = (const float*)d_in[31];

  // workspace layout (floats); total 13,296,832 f = 53.2 MB
  float* wsf    = (float*)d_ws;
  float* ssb    = wsf;                     // 4 x 48  scale/shift per layer
  float* Qv     = wsf + 192;               // 65536
  unsigned short* Wf = (unsigned short*)(wsf + 65728);  // 3 x 65536 bf16
  float* pstats = wsf + 164032;            // 76800 (max 1600 blocks x 48)
  float* y1     = wsf + 240832;            // 9,830,400
  float* Abuf   = y1;                      // alias: y1 dead after conv2
  float* Bmbuf  = y1 + 1638400;
  float* y2     = wsf + 10071232;          // 2,457,600
  float* gpart  = y2;                      // alias: y2 dead after conv3
  float* y3     = wsf + 12528832;          // 614,400
  float* y4     = wsf + 13143232;          // 153,600

  conv_relu_stats<3,24><<<dim3(1600,1), 256, 0, stream>>>(x,  nullptr,  cw1, cb1, y1, pstats, 80,80,40,40);
  bn_reduce_finalize<<<24, 256, 0, stream>>>(pstats, 1600, bg1, bb1, ssb+0,   1.f/409600.f);
  conv_relu_stats<24,8><<<dim3(400,3),  256, 0, stream>>>(y1, ssb+0,   cw2, cb2, y2, pstats, 40,40,20,20);
  bn_reduce_finalize<<<24, 256, 0, stream>>>(pstats, 400,  bg2, bb2, ssb+48,  1.f/102400.f);
  conv_relu_stats<24,8><<<dim3(100,3),  256, 0, stream>>>(y2, ssb+48,  cw3, cb3, y3, pstats, 20,20,10,10);
  bn_reduce_finalize<<<24, 256, 0, stream>>>(pstats, 100,  bg3, bb3, ssb+96,  1.f/25600.f);
  conv_relu_stats<24,8><<<dim3(25,3),   256, 0, stream>>>(y3, ssb+96,  cw4, cb4, y4, pstats, 10,10,5,5);
  bn_reduce_finalize<<<24, 256, 0, stream>>>(pstats, 25,   bg4, bb4, ssb+144, 1.f/6400.f);

  prep_w<<<256, 256, 0, stream>>>(gw2, Wf);
  prep_w<<<256, 256, 0, stream>>>(gw3, Wf + 65536);
  prep_w<<<256, 256, 0, stream>>>(gw4, Wf + 131072);
  build_Qv<<<256, 256, 0, stream>>>(qst, gw1, gb1, Qv);
  build_AB<<<6400, 256, 0, stream>>>(y4, ssb+144, gw1, Abuf, Bmbuf);

  g_fused<<<2560, 256, 0, stream>>>(Abuf, Bmbuf, Qv, Wf, gb2, gb3, gb4, gpart);
  f_phi<<<256, 256, 0, stream>>>(gpart, fw1, fb1, fw2, fb2, fw3, fb3, (float*)d_out);
}

// Round 3
// 370.058 us; speedup vs baseline: 1.2810x; 1.2810x over previous
//
#include <hip/hip_runtime.h>
#include <hip/hip_bf16.h>

// RelationalNet forward, MI355X (gfx950).
// conv1..4 (+BN folded into consumer) -> factorized g layer-1 (A[q]+Bm[p]+Qv)
// -> g_fused: 128 rows/block, 8 waves, 3 layers of 256x256 bf16 MFMA with
//    double-buffered global_load_lds weight staging -> masked row-sum
// -> f_phi + log_softmax.
// Workspace requirement: 13,296,832 floats = 53.2 MB.

typedef __attribute__((ext_vector_type(8))) short short8;
typedef __attribute__((ext_vector_type(4))) float floatx4;

__device__ __forceinline__ unsigned short f2bf(float v){
  union { float f; unsigned int u; } c; c.f = v;
  unsigned int u = c.u;
  u += 0x7FFFu + ((u >> 16) & 1u);   // round-to-nearest-even
  return (unsigned short)(u >> 16);
}

__device__ __forceinline__ void gload_lds16(const void* g, void* l){
  __builtin_amdgcn_global_load_lds((const __attribute__((address_space(1))) void*)g,
                                   (__attribute__((address_space(3))) void*)l, 16, 0, 0);
}

// ---------------- conv + relu + per-block BN partial stats ----------------
template<int CI, int COG>
__global__ __launch_bounds__(256) void conv_relu_stats(
    const float* __restrict__ in, const float* __restrict__ ss,
    const float* __restrict__ cw, const float* __restrict__ cb,
    float* __restrict__ out, float* __restrict__ pstats,
    int H, int W, int OH, int OW)
{
  const int co0 = blockIdx.y * COG;
  __shared__ float wsm[COG*CI*9];
  __shared__ float ssm[2*CI];
  __shared__ float psum[4*COG], psum2[4*COG];
  const int tid = threadIdx.x;
  for (int j = tid; j < COG*CI*9; j += 256) wsm[j] = cw[co0*CI*9 + j];
  if (ss) { for (int j = tid; j < 2*CI; j += 256) ssm[j] = ss[j]; }
  else    { for (int j = tid; j < 2*CI; j += 256) ssm[j] = (j < CI) ? 1.f : 0.f; }
  __syncthreads();
  const int idx = blockIdx.x*256 + tid;          // grids are exact multiples of 256
  const int ow = idx % OW; const int t2 = idx / OW;
  const int oh = t2 % OH;  const int b  = t2 / OH;
  float accv[COG];
  #pragma unroll
  for (int g = 0; g < COG; g++) accv[g] = cb[co0+g];
  for (int ci = 0; ci < CI; ci++){
    const float* ip = in + ((long)(b*CI+ci))*H*W;
    const float sc = ssm[ci], sh = ssm[CI+ci];
    #pragma unroll
    for (int kh = 0; kh < 3; kh++){
      const int ih = oh*2 - 1 + kh;
      if ((unsigned)ih >= (unsigned)H) continue;      // zero-padding: contributes 0
      #pragma unroll
      for (int kw = 0; kw < 3; kw++){
        const int iw = ow*2 - 1 + kw;
        if ((unsigned)iw >= (unsigned)W) continue;
        const float v = ip[ih*W + iw] * sc + sh;       // folded BN of previous layer
        #pragma unroll
        for (int g = 0; g < COG; g++)
          accv[g] += v * wsm[(g*CI+ci)*9 + kh*3 + kw];
      }
    }
  }
  const int wave = tid >> 6, lane = tid & 63;
  #pragma unroll
  for (int g = 0; g < COG; g++){
    const float v = fmaxf(accv[g], 0.f);
    out[(((long)b*24 + co0+g)*OH + oh)*OW + ow] = v;
    float s = v, s2 = v*v;
    for (int off = 32; off; off >>= 1){ s += __shfl_down(s, off); s2 += __shfl_down(s2, off); }
    if (lane == 0){ psum[wave*COG+g] = s; psum2[wave*COG+g] = s2; }
  }
  __syncthreads();
  if (tid < COG){
    float S = 0.f, S2 = 0.f;
    #pragma unroll
    for (int w = 0; w < 4; w++){ S += psum[w*COG+tid]; S2 += psum2[w*COG+tid]; }
    pstats[blockIdx.x*48 + co0 + tid]      = S;
    pstats[blockIdx.x*48 + 24 + co0 + tid] = S2;
  }
}

// ------------- reduce per-block stats -> scale/shift (gamma*(x-m)*rs+beta) -------------
__global__ __launch_bounds__(256) void bn_reduce_finalize(
    const float* __restrict__ pstats, int nblk,
    const float* __restrict__ gamma, const float* __restrict__ beta,
    float* __restrict__ ss, float invN)
{
  const int c = blockIdx.x;           // 0..23
  const int tid = threadIdx.x;
  float s = 0.f, s2 = 0.f;
  for (int j = tid; j < nblk; j += 256){ s += pstats[j*48 + c]; s2 += pstats[j*48 + 24 + c]; }
  for (int off = 32; off; off >>= 1){ s += __shfl_down(s, off); s2 += __shfl_down(s2, off); }
  __shared__ float ps[4], ps2[4];
  const int wave = tid >> 6, lane = tid & 63;
  if (lane == 0){ ps[wave] = s; ps2[wave] = s2; }
  __syncthreads();
  if (tid == 0){
    const float S  = ps[0]+ps[1]+ps[2]+ps[3];
    const float S2 = ps2[0]+ps2[1]+ps2[2]+ps2[3];
    const float mean = S * invN;
    const float var  = S2 * invN - mean*mean;      // biased var (ddof=0), matches jnp.var
    const float rs   = rsqrtf(var + 1e-5f);
    const float sc   = gamma[c] * rs;
    ss[c]      = sc;
    ss[24 + c] = beta[c] - mean * sc;
  }
}

// ------------- gw2/3/4 f32 -> bf16 in MFMA B-fragment order -------------
// wf[((kk*16 + t)*64 + lane)*8 + i] = W[kk*32 + (lane>>4)*8 + i][t*16 + (lane&15)]
__global__ __launch_bounds__(256) void prep_w(
    const float* __restrict__ gw, unsigned short* __restrict__ wf)
{
  const int idx = blockIdx.x*256 + threadIdx.x;   // 65536 total
  const int i = idx & 7, lane = (idx >> 3) & 63, t = (idx >> 9) & 15, kk = idx >> 13;
  const int k = kk*32 + (lane >> 4)*8 + i;
  const int c = t*16 + (lane & 15);
  wf[idx] = f2bf(gw[k*256 + c]);
}

// ------------- Qv[b][n] = gb1[n] + qst[b] @ gw1[52:63] -------------
__global__ __launch_bounds__(256) void build_Qv(
    const float* __restrict__ qst, const float* __restrict__ gw1,
    const float* __restrict__ gb1, float* __restrict__ Qv)
{
  const int b = blockIdx.x, n = threadIdx.x;
  float acc = gb1[n];
  #pragma unroll
  for (int j = 0; j < 11; j++) acc += qst[b*11 + j] * gw1[(52 + j)*256 + n];
  Qv[b*256 + n] = acc;
}

// ------------- A[bq] = obj[b,q] @ gw1[0:26] ; Bm[bq] = obj[b,q] @ gw1[26:52] -------------
__global__ __launch_bounds__(256) void build_AB(
    const float* __restrict__ y4, const float* __restrict__ ss4,
    const float* __restrict__ gw1, float* __restrict__ A, float* __restrict__ Bm)
{
  const int bq = blockIdx.x;            // 0..6399
  const int b = bq / 25, q = bq % 25;
  __shared__ float orow[26];
  const int tid = threadIdx.x;
  if (tid < 24)        orow[tid] = ss4[tid] * y4[((long)(b*24 + tid))*25 + q] + ss4[24 + tid];
  else if (tid == 24)  orow[24] = (float)(q/5 - 2) * 0.5f;
  else if (tid == 25)  orow[25] = (float)(q%5 - 2) * 0.5f;
  __syncthreads();
  float a = 0.f, bb = 0.f;
  #pragma unroll
  for (int c = 0; c < 26; c++){
    const float o = orow[c];
    a  += o * gw1[c*256 + tid];
    bb += o * gw1[(26 + c)*256 + tid];
  }
  A [(long)bq*256 + tid] = a;
  Bm[(long)bq*256 + tid] = bb;
}

// ------------- fused g_theta layers 2..4 + masked row-sum -------------
// block: 128 pair-rows of one batch, 8 waves (2M x 4N); wave (wm,wn) owns
// rows [wm*64,+64) x cols [wn*64,+64). act: bf16 [128][256] LDS, XOR-swizzled
// (byte ^= (row&7)<<4). Weights: fragment-ordered global, staged in 16 KB
// K=32 chunks (chunk byte size 16384), double-buffered, via global_load_lds(16)
// issued one step ahead; one __syncthreads per step (24 steps over 3 layers).
// Per-wave staging slice: [wave*1024, +1024) and [8192 + wave*1024, +1024).
__global__ __launch_bounds__(512) void g_fused(
    const float* __restrict__ A, const float* __restrict__ Bm, const float* __restrict__ Qv,
    const unsigned short* __restrict__ Wf,
    const float* __restrict__ gb2, const float* __restrict__ gb3, const float* __restrict__ gb4,
    float* __restrict__ gpart)
{
  __shared__ __align__(16) short act[128*256];    // 64 KB
  __shared__ __align__(16) short wt[2][32*256];   // 2 x 16 KB (buf0 reused as f32 scratch)
  const int tid = threadIdx.x;
  const int bidx = blockIdx.x;
  const int b = bidx / 5, blk = bidx % 5;
  const int rowbase = blk * 128;
  const int nrows = min(128, 625 - rowbase);      // last block: 113
  char* actB = (char*)act;
  const int wave = tid >> 6, lane = tid & 63;
  const int lmod = lane & 15, ldiv = lane >> 4;
  const int wm = wave >> 2, wn = wave & 3;        // 2 x 4 wave grid

  // stage chunk 0 early (overlaps with the f32 init loads)
  {
    const char* g = (const char*)Wf + wave*1024 + lane*16;
    char* l = (char*)wt[0] + wave*1024;
    gload_lds16(g, l);
    gload_lds16(g + 8192, l + 8192);
  }

  // ---- layer-1 activations: act = relu(A[q] + Bm[p] + Qv), bf16, swizzled ----
  // thread -> (row r = tid>>2, lane-quad q4 = tid&3); iter j: cols [j*16 + q4*4, +4)
  // so the 4 lanes of a row write one contiguous 32B run (2-way bank alias = free).
  {
    const int r  = tid >> 2;
    const int q4 = tid & 3;
    if (r < nrows){
      const int row = rowbase + r;                // pair index p*25+q
      const float* ap = A  + ((long)(b*25 + row % 25))*256 + q4*4;
      const float* bp = Bm + ((long)(b*25 + row / 25))*256 + q4*4;
      const float* qp = Qv + b*256 + q4*4;
      #pragma unroll
      for (int j = 0; j < 16; j++){
        const int c = j*16;
        floatx4 av = *(const floatx4*)(ap + c);
        floatx4 bv = *(const floatx4*)(bp + c);
        floatx4 qv = *(const floatx4*)(qp + c);
        unsigned int p0 = (unsigned int)f2bf(fmaxf(av.x+bv.x+qv.x, 0.f))
                        | ((unsigned int)f2bf(fmaxf(av.y+bv.y+qv.y, 0.f)) << 16);
        unsigned int p1 = (unsigned int)f2bf(fmaxf(av.z+bv.z+qv.z, 0.f))
                        | ((unsigned int)f2bf(fmaxf(av.w+bv.w+qv.w, 0.f)) << 16);
        const int byte = (r*512 + (c + q4*4)*2) ^ ((r & 7) << 4);
        *(uint2*)(actB + byte) = make_uint2(p0, p1);
      }
    } else {
      #pragma unroll
      for (int j = 0; j < 16; j++){
        const int byte = (r*512 + (j*16 + q4*4)*2) ^ ((r & 7) << 4);
        *(uint2*)(actB + byte) = make_uint2(0u, 0u); // padded rows: zero (masked at sum)
      }
    }
  }
  __syncthreads();   // act ready; stage-0 drained (vmcnt(0) in barrier)

  floatx4 acc[4][4];
  for (int s = 0; s < 24; s++){
    const int L = s >> 3, kk = s & 7, p = s & 1;
    if (kk == 0){
      #pragma unroll
      for (int m = 0; m < 4; m++)
        #pragma unroll
        for (int n = 0; n < 4; n++)
          acc[m][n] = (floatx4){0.f,0.f,0.f,0.f};
    }
    if (s < 23){   // stage chunk s+1 into the other buffer
      const char* g = (const char*)Wf + (s+1)*16384 + wave*1024 + lane*16;
      char* l = (char*)wt[p ^ 1] + wave*1024;
      gload_lds16(g, l);
      gload_lds16(g + 8192, l + 8192);
    }
    short8 af[4];
    #pragma unroll
    for (int m = 0; m < 4; m++){
      const int arow  = wm*64 + m*16 + lmod;
      const int abyte = (arow*512 + kk*64 + ldiv*16) ^ ((arow & 7) << 4);
      af[m] = *(const short8*)(actB + abyte);
    }
    const short8* wfr = (const short8*)wt[p];
    #pragma unroll
    for (int n = 0; n < 4; n++){
      const short8 bfv = wfr[(wn*4 + n)*64 + lane];
      #pragma unroll
      for (int m = 0; m < 4; m++)
        acc[m][n] = __builtin_amdgcn_mfma_f32_16x16x32_bf16(af[m], bfv, acc[m][n], 0, 0, 0);
    }
    __syncthreads();   // drains stage s+1; also covers WAR on wt[p] and act reads

    if (kk == 7){
      if (L < 2){
        const float* bias = (L == 0) ? gb2 : gb3;
        // D layout: row = m*16 + ldiv*4 + i, col = (wn*4+n)*16 + lmod   [m89]
        #pragma unroll
        for (int n = 0; n < 4; n++){
          const int c = (wn*4 + n)*16 + lmod;
          const float bv = bias[c];
          #pragma unroll
          for (int m = 0; m < 4; m++){
            #pragma unroll
            for (int i = 0; i < 4; i++){
              const int row = wm*64 + m*16 + ldiv*4 + i;
              const float v = fmaxf(acc[m][n][i] + bv, 0.f);
              const int byte = (row*512 + c*2) ^ ((row & 7) << 4);
              *(short*)(actB + byte) = (short)f2bf(v);
            }
          }
        }
        __syncthreads();  // new act visible before next layer's reads
      } else {
        float* scratch = (float*)wt[0];           // 512 floats used; no pending stages
        #pragma unroll
        for (int n = 0; n < 4; n++){
          const int c = (wn*4 + n)*16 + lmod;
          const float bv = gb4[c];
          float sv = 0.f;
          #pragma unroll
          for (int m = 0; m < 4; m++){
            #pragma unroll
            for (int i = 0; i < 4; i++){
              const int row = wm*64 + m*16 + ldiv*4 + i;
              const float v = fmaxf(acc[m][n][i] + bv, 0.f);
              if (row < nrows) sv += v;           // mask padded rows
            }
          }
          sv += __shfl_xor(sv, 16);
          sv += __shfl_xor(sv, 32);
          if (ldiv == 0) scratch[wm*256 + c] = sv;
        }
        __syncthreads();
        if (tid < 256) gpart[(long)bidx*256 + tid] = scratch[tid] + scratch[256 + tid];
      }
    }
  }
}

// ------------- reduce partials + f_phi + log_softmax -------------
__global__ __launch_bounds__(256) void f_phi(
    const float* __restrict__ gpart,
    const float* __restrict__ fw1, const float* __restrict__ fb1,
    const float* __restrict__ fw2, const float* __restrict__ fb2,
    const float* __restrict__ fw3, const float* __restrict__ fb3,
    float* __restrict__ out)
{
  const int b = blockIdx.x, n = threadIdx.x;
  __shared__ float bufA[256], bufB[256], lg[10];
  float g = 0.f;
  #pragma unroll
  for (int j = 0; j < 5; j++) g += gpart[((long)(b*5 + j))*256 + n];
  bufA[n] = g;
  __syncthreads();
  float acc = fb1[n];
  for (int k = 0; k < 256; k++) acc += bufA[k] * fw1[k*256 + n];
  bufB[n] = fmaxf(acc, 0.f);
  __syncthreads();
  acc = fb2[n];
  for (int k = 0; k < 256; k++) acc += bufB[k] * fw2[k*256 + n];
  __syncthreads();
  bufA[n] = fmaxf(acc, 0.f);
  __syncthreads();
  if (n < 10){
    float a3 = fb3[n];
    for (int k = 0; k < 256; k++) a3 += bufA[k] * fw3[k*10 + n];
    lg[n] = a3;
  }
  __syncthreads();
  if (n < 10){
    float m = lg[0];
    #pragma unroll
    for (int j = 1; j < 10; j++) m = fmaxf(m, lg[j]);
    float s = 0.f;
    #pragma unroll
    for (int j = 0; j < 10; j++) s += expf(lg[j] - m);
    out[b*10 + n] = lg[n] - m - logf(s);
  }
}

extern "C" void kernel_launch(void* const* d_in, const int* in_sizes, int n_in,
                              void* d_out, int out_size, void* d_ws, size_t ws_size,
                              hipStream_t stream)
{
  const float* x   = (const float*)d_in[0];
  const float* qst = (const float*)d_in[1];
  const float* cw1 = (const float*)d_in[2];
  const float* cb1 = (const float*)d_in[3];
  const float* bg1 = (const float*)d_in[4];
  const float* bb1 = (const float*)d_in[5];
  const float* cw2 = (const float*)d_in[6];
  const float* cb2 = (const float*)d_in[7];
  const float* bg2 = (const float*)d_in[8];
  const float* bb2 = (const float*)d_in[9];
  const float* cw3 = (const float*)d_in[10];
  const float* cb3 = (const float*)d_in[11];
  const float* bg3 = (const float*)d_in[12];
  const float* bb3 = (const float*)d_in[13];
  const float* cw4 = (const float*)d_in[14];
  const float* cb4 = (const float*)d_in[15];
  const float* bg4 = (const float*)d_in[16];
  const float* bb4 = (const float*)d_in[17];
  const float* gw1 = (const float*)d_in[18];
  const float* gb1 = (const float*)d_in[19];
  const float* gw2 = (const float*)d_in[20];
  const float* gb2 = (const float*)d_in[21];
  const float* gw3 = (const float*)d_in[22];
  const float* gb3 = (const float*)d_in[23];
  const float* gw4 = (const float*)d_in[24];
  const float* gb4 = (const float*)d_in[25];
  const float* fw1 = (const float*)d_in[26];
  const float* fb1 = (const float*)d_in[27];
  const float* fw2 = (const float*)d_in[28];
  const float* fb2 = (const float*)d_in[29];
  const float* fw3 = (const float*)d_in[30];
  const float* fb3 = (const float*)d_in[31];

  // workspace layout (floats); total 13,296,832 f = 53.2 MB
  float* wsf    = (float*)d_ws;
  float* ssb    = wsf;                     // 4 x 48  scale/shift per layer
  float* Qv     = wsf + 192;               // 65536
  unsigned short* Wf = (unsigned short*)(wsf + 65728);  // 3 x 65536 bf16
  float* pstats = wsf + 164032;            // 76800 (max 1600 blocks x 48)
  float* y1     = wsf + 240832;            // 9,830,400
  float* Abuf   = y1;                      // alias: y1 dead after conv2
  float* Bmbuf  = y1 + 1638400;
  float* y2     = wsf + 10071232;          // 2,457,600
  float* gpart  = y2;                      // alias: y2 dead after conv3 (1280x256)
  float* y3     = wsf + 12528832;          // 614,400
  float* y4     = wsf + 13143232;          // 153,600

  conv_relu_stats<3,24><<<dim3(1600,1), 256, 0, stream>>>(x,  nullptr,  cw1, cb1, y1, pstats, 80,80,40,40);
  bn_reduce_finalize<<<24, 256, 0, stream>>>(pstats, 1600, bg1, bb1, ssb+0,   1.f/409600.f);
  conv_relu_stats<24,8><<<dim3(400,3),  256, 0, stream>>>(y1, ssb+0,   cw2, cb2, y2, pstats, 40,40,20,20);
  bn_reduce_finalize<<<24, 256, 0, stream>>>(pstats, 400,  bg2, bb2, ssb+48,  1.f/102400.f);
  conv_relu_stats<24,8><<<dim3(100,3),  256, 0, stream>>>(y2, ssb+48,  cw3, cb3, y3, pstats, 20,20,10,10);
  bn_reduce_finalize<<<24, 256, 0, stream>>>(pstats, 100,  bg3, bb3, ssb+96,  1.f/25600.f);
  conv_relu_stats<24,8><<<dim3(25,3),   256, 0, stream>>>(y3, ssb+96,  cw4, cb4, y4, pstats, 10,10,5,5);
  bn_reduce_finalize<<<24, 256, 0, stream>>>(pstats, 25,   bg4, bb4, ssb+144, 1.f/6400.f);

  prep_w<<<256, 256, 0, stream>>>(gw2, Wf);
  prep_w<<<256, 256, 0, stream>>>(gw3, Wf + 65536);
  prep_w<<<256, 256, 0, stream>>>(gw4, Wf + 131072);
  build_Qv<<<256, 256, 0, stream>>>(qst, gw1, gb1, Qv);
  build_AB<<<6400, 256, 0, stream>>>(y4, ssb+144, gw1, Abuf, Bmbuf);

  g_fused<<<1280, 512, 0, stream>>>(Abuf, Bmbuf, Qv, Wf, gb2, gb3, gb4, gpart);
  f_phi<<<256, 256, 0, stream>>>(gpart, fw1, fb1, fw2, fb2, fw3, fb3, (float*)d_out);
}